// Round 2
// baseline (131.368 us; speedup 1.0000x reference)
//
#include <hip/hip_runtime.h>
#include <cfloat>

typedef unsigned long long u64;

#define CDESC 32
#define N0 4096
#define N1 512

// sign-transformed float bits: monotone u32 over the float total order
__device__ __forceinline__ unsigned fbits_mono(float d) {
    unsigned b = __float_as_uint(d);
    return (d >= 0.f) ? (b | 0x80000000u) : ~b;
}

__device__ __forceinline__ void wave_reduce_atomic(float v, float* acc) {
#pragma unroll
    for (int off = 32; off > 0; off >>= 1) v += __shfl_down(v, off, 64);
    if ((threadIdx.x & 63) == 0) atomicAdd(acc, v);
}

// ======================= K1: fused x-filter (both stages) + transpose =======================
// blocks 0..767 (x2 sides): one (channel, z) input plane staged to LDS once;
// compute BOTH S=16 (R=4) and S=8 (R=8) x-filter outputs from it.
// R9: sRow padded to 65-float row stride (bank = y + tap -> 2 lanes/bank, free).
// blocks 768..1055: descriptor transpose [b][32][N] -> [b][N][32].
__global__ __launch_bounds__(256) void pass1_fused(
        const float* __restrict__ csrc, const float* __restrict__ ctgt,
        const float* __restrict__ sd0, const float* __restrict__ td0,
        const float* __restrict__ sd1, const float* __restrict__ td1,
        float* __restrict__ t16a, float* __restrict__ t16b,
        float* __restrict__ t8a,  float* __restrict__ t8b,
        float* __restrict__ sd0T, float* __restrict__ td0T,
        float* __restrict__ sd1T, float* __restrict__ td1T,
        float* __restrict__ acc) {
    __shared__ __align__(16) float sRow[65 * 64];  // padded 64x64 plane (16.25 KB)
    const int tid = threadIdx.x;
    const int bx  = blockIdx.x, by = blockIdx.y;
    if (by == 0 && bx == 0 && tid < 4) acc[tid] = 0.f;

    if (bx < 768) {
        int bc = bx >> 6, z = bx & 63;             // channel-plane, z-slice
        const float* in = by ? ctgt : csrc;
        float* o16 = by ? t16b : t16a;
        float* o8  = by ? t8b  : t8a;
        const float4* src = (const float4*)(in + (size_t)(bc * 64 + z) * 4096);
#pragma unroll
        for (int k = 0; k < 4; ++k) {              // coalesced 16 KB stage, padded rows
            float4 v = src[tid + k * 256];
            int g = tid + k * 256;                 // float4 index 0..1023
            int y = g >> 4, j = (g & 15) * 4;      // row, col (j%4==0, no pad crossing)
            float* p = &sRow[y * 65 + j];          // scalar writes: 2-way banks (free)
            p[0] = v.x; p[1] = v.y; p[2] = v.z; p[3] = v.w;
        }
        __syncthreads();
#pragma unroll
        for (int k = 0; k < 6; ++k) {              // 1536 outputs, 6/thread
            int o = tid + k * 256;
            if (o < 1024) {                        // S=16, R=4 (k=0..3: no divergence)
                int y = o >> 4, xo = o & 15;
                int j0 = 4 * xo - 2;
                float sum = 0.f, wsum = 0.f;
#pragma unroll
                for (int t = 0; t < 8; ++t) {
                    int j = j0 + t;
                    float w = 1.f - fabsf((float)t - 3.5f) / 4.f;
                    if (j >= 0 && j < 64) { sum = fmaf(w, sRow[y * 65 + j], sum); wsum += w; }
                }
                o16[bc * 65536 + z * 1024 + y * 16 + xo] = sum / wsum;
            } else {                               // S=8, R=8 (k=4,5)
                int o2 = o - 1024;
                int y = o2 >> 3, xo = o2 & 7;
                int j0 = 8 * xo - 4;
                float sum = 0.f, wsum = 0.f;
#pragma unroll
                for (int t = 0; t < 16; ++t) {
                    int j = j0 + t;
                    float w = 1.f - fabsf((float)t - 7.5f) / 8.f;
                    if (j >= 0 && j < 64) { sum = fmaf(w, sRow[y * 65 + j], sum); wsum += w; }
                }
                o8[bc * 32768 + z * 512 + y * 8 + xo] = sum / wsum;
            }
        }
    } else {
        // ---- transpose [b][32][N] -> [b][N][32], 64-point tiles (verified R7) ----
        __shared__ float tile[64 * 33];
        int tl = bx - 768;                         // 0..287
        const float* din; float* dout; int N, b, n0;
        if (tl < 256) { din = by ? td0 : sd0; dout = by ? td0T : sd0T;
                        N = N0; b = tl >> 6; n0 = (tl & 63) * 64; }
        else { tl -= 256; din = by ? td1 : sd1; dout = by ? td1T : sd1T;
               N = N1; b = tl >> 3; n0 = (tl & 7) * 64; }
#pragma unroll
        for (int i = 0; i < 8; ++i) {              // load: coalesced 64-float rows
            int idx = tid + i * 256;
            int c = idx >> 6, j = idx & 63;
            tile[j * 33 + c] = din[((size_t)b * CDESC + c) * N + n0 + j];
        }
        __syncthreads();
#pragma unroll
        for (int i = 0; i < 8; ++i) {              // store: contiguous 32-float points
            int idx = tid + i * 256;
            int p = idx >> 5, c = idx & 31;
            dout[((size_t)b * N + n0 + p) * CDESC + c] = tile[p * 33 + c];
        }
    }
}

// K2: both stages' y/z-filter, 8 sub-threads per point (verified R6/R7).
// R9: target-side points written PRE-TRANSFORMED (-2x,-2y,-2z,|t|^2) since
// pt0/pt1 are only ever consumed as argmin candidates.
__global__ __launch_bounds__(256) void pass2_both(
        const float* __restrict__ t16a, const float* __restrict__ t16b,
        const float* __restrict__ t8a,  const float* __restrict__ t8b,
        float4* __restrict__ ps0, float4* __restrict__ pt0,
        float4* __restrict__ ps1, float4* __restrict__ pt1) {
    int gid = blockIdx.x * 256 + threadIdx.x;
    if (blockIdx.x < 1024) {
        int sub = gid & 7, p = gid >> 3;
        int side = p >> 14, r = p & 16383;
        int b = r >> 12, n = r & 4095;
        int x = n & 15, y = (n >> 4) & 15, z = n >> 8;
        const float* t = side ? t16b : t16a;
        float wy[8]; int jy[8];
        float wys = 0.f, wzs = 0.f;
#pragma unroll
        for (int tt = 0; tt < 8; ++tt) {
            float w = 1.f - fabsf((float)tt - 3.5f) * 0.25f;
            int j = 4 * y - 2 + tt;
            bool v = (unsigned)j < 64u;
            wy[tt] = v ? w : 0.f; jy[tt] = v ? j : 0; wys += wy[tt];
            int jz = 4 * z - 2 + tt;
            if ((unsigned)jz < 64u) wzs += w;
        }
        float a0 = 0.f, a1 = 0.f, a2 = 0.f;
        {
            float wz = 1.f - fabsf((float)sub - 3.5f) * 0.25f;
            int jz = 4 * z - 2 + sub;
            if ((unsigned)jz < 64u) {
                const float* bz = t + (size_t)b * 196608 + jz * 1024 + x;
#pragma unroll
                for (int ty = 0; ty < 8; ++ty) {
                    float w = wz * wy[ty];
                    const float* pr = bz + jy[ty] * 16;
                    a0 = fmaf(w, pr[0],      a0);
                    a1 = fmaf(w, pr[65536],  a1);
                    a2 = fmaf(w, pr[131072], a2);
                }
            }
        }
#pragma unroll
        for (int m = 1; m < 8; m <<= 1) {
            a0 += __shfl_xor(a0, m, 64);
            a1 += __shfl_xor(a1, m, 64);
            a2 += __shfl_xor(a2, m, 64);
        }
        if (sub == 0) {
            float inv = 1.f / (wys * wzs);
            a0 *= inv; a1 *= inv; a2 *= inv;
            float sq = a0 * a0 + a1 * a1 + a2 * a2;
            if (side) pt0[b * N0 + n] = make_float4(-2.f * a0, -2.f * a1, -2.f * a2, sq);
            else      ps0[b * N0 + n] = make_float4(a0, a1, a2, sq);
        }
    } else {
        int g = gid - 262144;
        int sub = g & 7, p = g >> 3;
        int side = p >> 11, r = p & 2047;
        int b = r >> 9, n = r & 511;
        int x = n & 7, y = (n >> 3) & 7, z = n >> 6;
        const float* t = side ? t8b : t8a;
        constexpr int CS = 64 * 64 * 8;
        float wy[16]; int jy[16];
        float wys = 0.f, wzs = 0.f;
#pragma unroll
        for (int tt = 0; tt < 16; ++tt) {
            float w = 1.f - fabsf((float)tt - 7.5f) * 0.125f;
            int j = 8 * y - 4 + tt;
            bool v = (unsigned)j < 64u;
            wy[tt] = v ? w : 0.f; jy[tt] = v ? j : 0; wys += wy[tt];
            int jz = 8 * z - 4 + tt;
            if ((unsigned)jz < 64u) wzs += w;
        }
        float a0 = 0.f, a1 = 0.f, a2 = 0.f;
#pragma unroll
        for (int k = 0; k < 2; ++k) {
            int tt = 2 * sub + k;
            float wz = 1.f - fabsf((float)tt - 7.5f) * 0.125f;
            int jz = 8 * z - 4 + tt;
            if ((unsigned)jz < 64u) {
                const float* bz = t + b * 3 * CS + jz * (64 * 8) + x;
#pragma unroll 1
                for (int ty = 0; ty < 16; ++ty) {
                    float w = wz * wy[ty];
                    const float* pr = bz + jy[ty] * 8;
                    a0 = fmaf(w, pr[0],      a0);
                    a1 = fmaf(w, pr[CS],     a1);
                    a2 = fmaf(w, pr[2 * CS], a2);
                }
            }
        }
#pragma unroll
        for (int m = 1; m < 8; m <<= 1) {
            a0 += __shfl_xor(a0, m, 64);
            a1 += __shfl_xor(a1, m, 64);
            a2 += __shfl_xor(a2, m, 64);
        }
        if (sub == 0) {
            float inv = 1.f / (wys * wzs);
            a0 *= inv; a1 *= inv; a2 *= inv;
            float sq = a0 * a0 + a1 * a1 + a2 * a2;
            if (side) pt1[b * N1 + n] = make_float4(-2.f * a0, -2.f * a1, -2.f * a2, sq);
            else      ps1[b * N1 + n] = make_float4(a0, a1, a2, sq);
        }
    }
}

// cosine of two point-major 32-float descriptors (coalesced float4 reads)
__device__ __forceinline__ float cos_pm(const float* __restrict__ sT,
                                        const float* __restrict__ tT,
                                        size_t si, size_t ti) {
    const float4* s = (const float4*)(sT + si * CDESC);
    const float4* t = (const float4*)(tT + ti * CDESC);
    float num = 0.f, s2 = 0.f, t2 = 0.f;
#pragma unroll
    for (int c = 0; c < 8; ++c) {
        float4 a = s[c], g = t[c];
        num = fmaf(a.x, g.x, fmaf(a.y, g.y, fmaf(a.z, g.z, fmaf(a.w, g.w, num))));
        s2  = fmaf(a.x, a.x, fmaf(a.y, a.y, fmaf(a.z, a.z, fmaf(a.w, a.w, s2))));
        t2  = fmaf(g.x, g.x, fmaf(g.y, g.y, fmaf(g.z, g.z, fmaf(g.w, g.w, t2))));
    }
    return num / (fmaxf(sqrtf(s2), 1e-8f) * fmaxf(sqrtf(t2), 1e-8f));
}

// d2 (minus the constant |s|^2 term) from a point P and a pre-transformed candidate Q
__device__ __forceinline__ float dist_pm(float4 P, float4 Q) {
    return fmaf(P.x, Q.x, fmaf(P.y, Q.y, fmaf(P.z, Q.z, Q.w)));
}

// ======================= K3: argmin + cosine =======================
// R10: candidates via SCALAR loads, not LDS. The candidate index is wave-uniform
// (readfirstlane-pinned window base + scalar loop var), pt0/pt1 are const
// __restrict__ kernel args -> LLVM uniformity+noclobber analysis emits
// s_load_dwordx4 (SMEM pipe, SGPR-resident Q). This removes all 1024 candidate
// ds_read_b128/wave AND the 64 KB LDS staging (occupancy cap + tail). Dist math
// unchanged: v_fma with one SGPR operand is legal. Values bit-identical (same
// data, same fmaf chain, same batch-16 strict-< + descending first-match scan).
// blocks 0..255: stage-0 (b, 64-point tile); 4 waves x 1024-candidate windows;
//   cross-wave combine via packed (mono(d)<<32|m) u64 keys in 2 KB static LDS.
// blocks 256..263: stage-1. Global 264-ticket on acc[2] finalizes out.
__global__ __launch_bounds__(256) void nn_cos_all(
        const float4* __restrict__ ps0, const float4* __restrict__ pt0,
        const float* __restrict__ sd0T, const float* __restrict__ td0T,
        const float4* __restrict__ ps1, const float4* __restrict__ pt1,
        const float* __restrict__ sd1T, const float* __restrict__ td1T,
        float* acc, float* __restrict__ out) {
    __shared__ u64 keys[256];
    const int tid = threadIdx.x;
    const int bx  = blockIdx.x;

    if (bx < 256) {
        int b = bx >> 6, ptile = bx & 63;
        int w = __builtin_amdgcn_readfirstlane(tid >> 6);  // compiler-provable uniform
        int lane = tid & 63;
        int n = ptile * 64 + lane;
        float4 P = ps0[b * N0 + n];
        const float4* tp = pt0 + b * N0 + w * 1024;        // uniform window base
        float best = FLT_MAX; int bbase = 0;
        for (int k0 = 0; k0 < 1024; k0 += 16) {
            float d[16];
#pragma unroll
            for (int u = 0; u < 16; ++u) {
                float4 Q = tp[k0 + u];                     // s_load_dwordx4 (uniform)
                d[u] = dist_pm(P, Q);
            }
            float e0 = fminf(d[0],  d[1]),  e1 = fminf(d[2],  d[3]);
            float e2 = fminf(d[4],  d[5]),  e3 = fminf(d[6],  d[7]);
            float e4 = fminf(d[8],  d[9]),  e5 = fminf(d[10], d[11]);
            float e6 = fminf(d[12], d[13]), e7 = fminf(d[14], d[15]);
            float f0 = fminf(e0, e1), f1 = fminf(e2, e3);
            float f2 = fminf(e4, e5), f3 = fminf(e6, e7);
            float bm = fminf(fminf(f0, f1), fminf(f2, f3));
            if (bm < best) { best = bm; bbase = k0; }      // strict <: keeps first batch
        }
        int bi = 0;
#pragma unroll
        for (int u = 15; u >= 0; --u) {                    // descending: ends at FIRST match
            float dv = dist_pm(P, tp[bbase + u]);
            if (dv == best) bi = u;
        }
        u64 key = ((u64)fbits_mono(best) << 32) | (unsigned)(w * 1024 + bbase + bi);
        keys[w * 64 + lane] = key;
        __syncthreads();
        if (tid < 64) {
            u64 k0 = keys[tid],       k1 = keys[tid + 64];
            u64 k2 = keys[tid + 128], k3 = keys[tid + 192];
            u64 ka = k0 < k1 ? k0 : k1;
            u64 kb = k2 < k3 ? k2 : k3;
            u64 kk = ka < kb ? ka : kb;                    // windows ascending + u64 min
            int nearest = (int)(unsigned)(kk & 0xFFFFFFFFull);
            int n2 = ptile * 64 + tid;
            float cosv = cos_pm(sd0T, td0T, (size_t)b * N0 + n2,
                                (size_t)b * N0 + nearest);
            wave_reduce_atomic(cosv, acc + 0);
        }
    } else {
        int bb = bx - 256;
        int b = bb >> 1;
        int n = (bb & 1) * 256 + tid;
        float4 P = ps1[b * N1 + n];
        const float4* tp = pt1 + b * N1;                   // uniform base
        float best = FLT_MAX; int bbase = 0;
        for (int k0 = 0; k0 < N1; k0 += 16) {
            float d[16];
#pragma unroll
            for (int u = 0; u < 16; ++u) {
                float4 Q = tp[k0 + u];                     // s_load_dwordx4 (uniform)
                d[u] = dist_pm(P, Q);
            }
            float e0 = fminf(d[0],  d[1]),  e1 = fminf(d[2],  d[3]);
            float e2 = fminf(d[4],  d[5]),  e3 = fminf(d[6],  d[7]);
            float e4 = fminf(d[8],  d[9]),  e5 = fminf(d[10], d[11]);
            float e6 = fminf(d[12], d[13]), e7 = fminf(d[14], d[15]);
            float f0 = fminf(e0, e1), f1 = fminf(e2, e3);
            float f2 = fminf(e4, e5), f3 = fminf(e6, e7);
            float bm = fminf(fminf(f0, f1), fminf(f2, f3));
            if (bm < best) { best = bm; bbase = k0; }
        }
        int bi = 0;
#pragma unroll
        for (int u = 15; u >= 0; --u) {
            float dv = dist_pm(P, tp[bbase + u]);
            if (dv == best) bi = u;
        }
        float cosv = cos_pm(sd1T, td1T, (size_t)b * N1 + n,
                            (size_t)b * N1 + bbase + bi);
        wave_reduce_atomic(cosv, acc + 1);
    }

    __syncthreads();                               // block's atomics all issued
    if (tid == 0) {
        __threadfence();
        unsigned old = atomicAdd((unsigned*)(acc + 2), 1u);
        if (old == 263u) {                         // last of 264 blocks
            float a0 = atomicAdd(acc + 0, 0.f);
            float a1 = atomicAdd(acc + 1, 0.f);
            out[0] = 1.f - 0.5f * (a0 * (1.f / 16384.f) + a1 * (1.f / 2048.f));
        }
    }
}

extern "C" void kernel_launch(void* const* d_in, const int* in_sizes, int n_in,
                              void* d_out, int out_size, void* d_ws, size_t ws_size,
                              hipStream_t stream) {
    const float* c_src = (const float*)d_in[0];   // [4,3,64,64,64]
    const float* c_tgt = (const float*)d_in[1];
    const float* sd0   = (const float*)d_in[2];   // [4,32,16,16,16]
    const float* td0   = (const float*)d_in[3];
    const float* sd1   = (const float*)d_in[4];   // [4,32,8,8,8]
    const float* td1   = (const float*)d_in[5];
    float* out = (float*)d_out;

    char* ws = (char*)d_ws;
    float* acc  = (float*)ws;                      // [0]=sum0 [1]=sum1 [2]=ticket
    float* t16a = (float*)(ws + 256);              // 786432 floats each
    float* t16b = t16a + 786432;
    float* t8a  = t16b + 786432;                   // 393216 floats each
    float* t8b  = t8a + 393216;
    float4* ps0 = (float4*)(t8b + 393216);         // 16384 float4
    float4* pt0 = ps0 + 16384;
    float4* ps1 = pt0 + 16384;                     // 2048 float4
    float4* pt1 = ps1 + 2048;
    float* sd0T = (float*)(pt1 + 2048);            // 524288 floats each
    float* td0T = sd0T + 524288;
    float* sd1T = td0T + 524288;                   // 65536 floats each
    float* td1T = sd1T + 65536;

    pass1_fused<<<dim3(1056, 2), 256, 0, stream>>>(c_src, c_tgt, sd0, td0, sd1, td1,
                                                   t16a, t16b, t8a, t8b,
                                                   sd0T, td0T, sd1T, td1T, acc);
    pass2_both<<<1152, 256, 0, stream>>>(t16a, t16b, t8a, t8b, ps0, pt0, ps1, pt1);
    nn_cos_all<<<264, 256, 0, stream>>>(ps0, pt0, sd0T, td0T, ps1, pt1,
                                        sd1T, td1T, acc, out);
}

// Round 3
// 116.480 us; speedup vs baseline: 1.1278x; 1.1278x over previous
//
#include <hip/hip_runtime.h>
#include <cfloat>

typedef unsigned long long u64;

#define CDESC 32
#define N0 4096
#define N1 512

// sign-transformed float bits: monotone u32 over the float total order
__device__ __forceinline__ unsigned fbits_mono(float d) {
    unsigned b = __float_as_uint(d);
    return (d >= 0.f) ? (b | 0x80000000u) : ~b;
}

__device__ __forceinline__ void wave_reduce_atomic(float v, float* acc) {
#pragma unroll
    for (int off = 32; off > 0; off >>= 1) v += __shfl_down(v, off, 64);
    if ((threadIdx.x & 63) == 0) atomicAdd(acc, v);
}

// ======================= K1: fused x+y filter (both stages) + transpose =======================
// R11: y-filter fused in-plane. blocks 0..767 (x2 sides): one (channel, z) input
// plane staged to LDS; x-filter to xf16[64y][16x]/xf8[64y][8x] (LDS, padded
// strides 17/9 to spread banks); then per-plane y-filter -> only [16y][16x] and
// [8y][8x] go to HBM. Intermediate traffic 9 MB -> 2 MB; pass2's 64-tap y,z
// gather becomes a pure 8/16-tap z-filter. Normalization now separable per axis
// (x: /wsum, y: /wys, z in pass2: /wzs) == jax.image.resize's per-axis form;
// weights are exact 1/8 / 1/16 multiples (interior sums 4.0/8.0 divide exactly).
// blocks 768..1055: descriptor transpose [b][32][N] -> [b][N][32] (verified R7).
__global__ __launch_bounds__(256) void pass1_fused(
        const float* __restrict__ csrc, const float* __restrict__ ctgt,
        const float* __restrict__ sd0, const float* __restrict__ td0,
        const float* __restrict__ sd1, const float* __restrict__ td1,
        float* __restrict__ x16a, float* __restrict__ x16b,
        float* __restrict__ x8a,  float* __restrict__ x8b,
        float* __restrict__ sd0T, float* __restrict__ td0T,
        float* __restrict__ sd1T, float* __restrict__ td1T,
        float* __restrict__ acc) {
    __shared__ __align__(16) float sRow[65 * 64];  // padded 64x64 plane (16.25 KB)
    __shared__ float xf16[64 * 17];                // x-filtered [y64][x16], pad 17
    __shared__ float xf8[64 * 9];                  // x-filtered [y64][x8],  pad 9
    const int tid = threadIdx.x;
    const int bx  = blockIdx.x, by = blockIdx.y;
    if (by == 0 && bx == 0 && tid < 4) acc[tid] = 0.f;

    if (bx < 768) {
        int bc = bx >> 6, z = bx & 63;             // channel-plane, z-slice
        const float* in = by ? ctgt : csrc;
        float* o16 = by ? x16b : x16a;
        float* o8  = by ? x8b  : x8a;
        const float4* src = (const float4*)(in + (size_t)(bc * 64 + z) * 4096);
#pragma unroll
        for (int k = 0; k < 4; ++k) {              // coalesced 16 KB stage, padded rows
            float4 v = src[tid + k * 256];
            int g = tid + k * 256;                 // float4 index 0..1023
            int y = g >> 4, j = (g & 15) * 4;      // row, col (j%4==0, no pad crossing)
            float* p = &sRow[y * 65 + j];          // scalar writes: 2-way banks (free)
            p[0] = v.x; p[1] = v.y; p[2] = v.z; p[3] = v.w;
        }
        __syncthreads();
#pragma unroll
        for (int k = 0; k < 6; ++k) {              // x-filter: 1536 vals, 6/thread
            int o = tid + k * 256;
            if (o < 1024) {                        // S=16, R=4 (k=0..3: no divergence)
                int y = o >> 4, xo = o & 15;
                int j0 = 4 * xo - 2;
                float sum = 0.f, wsum = 0.f;
#pragma unroll
                for (int t = 0; t < 8; ++t) {
                    int j = j0 + t;
                    float w = 1.f - fabsf((float)t - 3.5f) / 4.f;
                    if (j >= 0 && j < 64) { sum = fmaf(w, sRow[y * 65 + j], sum); wsum += w; }
                }
                xf16[y * 17 + xo] = sum / wsum;
            } else {                               // S=8, R=8 (k=4,5)
                int o2 = o - 1024;
                int y = o2 >> 3, xo = o2 & 7;
                int j0 = 8 * xo - 4;
                float sum = 0.f, wsum = 0.f;
#pragma unroll
                for (int t = 0; t < 16; ++t) {
                    int j = j0 + t;
                    float w = 1.f - fabsf((float)t - 7.5f) / 8.f;
                    if (j >= 0 && j < 64) { sum = fmaf(w, sRow[y * 65 + j], sum); wsum += w; }
                }
                xf8[y * 9 + xo] = sum / wsum;
            }
        }
        __syncthreads();
        {                                          // y-filter S=16: 256 outs, 1/thread
            int y2 = tid >> 4, x = tid & 15;
            int j0 = 4 * y2 - 2;
            float sum = 0.f, wsum = 0.f;
#pragma unroll
            for (int t = 0; t < 8; ++t) {
                int j = j0 + t;
                float w = 1.f - fabsf((float)t - 3.5f) / 4.f;
                if (j >= 0 && j < 64) { sum = fmaf(w, xf16[j * 17 + x], sum); wsum += w; }
            }
            o16[bc * 16384 + z * 256 + y2 * 16 + x] = sum / wsum;  // coalesced 1 KB
        }
        if (tid < 64) {                            // y-filter S=8: 64 outs
            int y2 = tid >> 3, x = tid & 7;
            int j0 = 8 * y2 - 4;
            float sum = 0.f, wsum = 0.f;
#pragma unroll
            for (int t = 0; t < 16; ++t) {
                int j = j0 + t;
                float w = 1.f - fabsf((float)t - 7.5f) / 8.f;
                if (j >= 0 && j < 64) { sum = fmaf(w, xf8[j * 9 + x], sum); wsum += w; }
            }
            o8[bc * 4096 + z * 64 + y2 * 8 + x] = sum / wsum;      // coalesced 256 B
        }
    } else {
        // ---- transpose [b][32][N] -> [b][N][32], 64-point tiles (verified R7) ----
        __shared__ float tile[64 * 33];
        int tl = bx - 768;                         // 0..287
        const float* din; float* dout; int N, b, n0;
        if (tl < 256) { din = by ? td0 : sd0; dout = by ? td0T : sd0T;
                        N = N0; b = tl >> 6; n0 = (tl & 63) * 64; }
        else { tl -= 256; din = by ? td1 : sd1; dout = by ? td1T : sd1T;
               N = N1; b = tl >> 3; n0 = (tl & 7) * 64; }
#pragma unroll
        for (int i = 0; i < 8; ++i) {              // load: coalesced 64-float rows
            int idx = tid + i * 256;
            int c = idx >> 6, j = idx & 63;
            tile[j * 33 + c] = din[((size_t)b * CDESC + c) * N + n0 + j];
        }
        __syncthreads();
#pragma unroll
        for (int i = 0; i < 8; ++i) {              // store: contiguous 32-float points
            int idx = tid + i * 256;
            int p = idx >> 5, c = idx & 31;
            dout[((size_t)b * N + n0 + p) * CDESC + c] = tile[p * 33 + c];
        }
    }
}

// ======================= K2: z-filter only (both stages) =======================
// R11: y already folded into pass1 -> pure 8-tap (S=16) / 16-tap (S=8) z-filter.
// Wave lanes span (x,y) -> contiguous 64-float (256 B) coalesced reads per tap.
// Target side written PRE-TRANSFORMED (-2x,-2y,-2z,|t|^2): exact *2/sign ops,
// bit-identical distances in K3.
__global__ __launch_bounds__(256) void pass2z(
        const float* __restrict__ x16a, const float* __restrict__ x16b,
        const float* __restrict__ x8a,  const float* __restrict__ x8b,
        float4* __restrict__ ps0, float4* __restrict__ pt0,
        float4* __restrict__ ps1, float4* __restrict__ pt1) {
    int gid = blockIdx.x * 256 + threadIdx.x;
    if (blockIdx.x < 128) {                        // stage-0: 32768 points
        int side = gid >> 14, r = gid & 16383;
        int b = r >> 12, n = r & 4095;
        int x = n & 15, y = (n >> 4) & 15, z = n >> 8;
        const float* t = side ? x16b : x16a;
        const float* base = t + (size_t)b * 49152 + y * 16 + x;  // b*3ch*16384
        float a0 = 0.f, a1 = 0.f, a2 = 0.f, wzs = 0.f;
#pragma unroll
        for (int tt = 0; tt < 8; ++tt) {
            float w = 1.f - fabsf((float)tt - 3.5f) * 0.25f;
            int jz = 4 * z - 2 + tt;
            if ((unsigned)jz < 64u) {
                const float* p = base + jz * 256;
                a0 = fmaf(w, p[0],     a0);
                a1 = fmaf(w, p[16384], a1);
                a2 = fmaf(w, p[32768], a2);
                wzs += w;
            }
        }
        float inv = 1.f / wzs;
        a0 *= inv; a1 *= inv; a2 *= inv;
        float sq = a0 * a0 + a1 * a1 + a2 * a2;
        if (side) pt0[b * N0 + n] = make_float4(-2.f * a0, -2.f * a1, -2.f * a2, sq);
        else      ps0[b * N0 + n] = make_float4(a0, a1, a2, sq);
    } else {                                       // stage-1: 4096 points
        int g = gid - 32768;
        int side = g >> 11, r = g & 2047;
        int b = r >> 9, n = r & 511;
        int x = n & 7, y = (n >> 3) & 7, z = n >> 6;
        const float* t = side ? x8b : x8a;
        const float* base = t + (size_t)b * 12288 + y * 8 + x;   // b*3ch*4096
        float a0 = 0.f, a1 = 0.f, a2 = 0.f, wzs = 0.f;
#pragma unroll
        for (int tt = 0; tt < 16; ++tt) {
            float w = 1.f - fabsf((float)tt - 7.5f) * 0.125f;
            int jz = 8 * z - 4 + tt;
            if ((unsigned)jz < 64u) {
                const float* p = base + jz * 64;
                a0 = fmaf(w, p[0],    a0);
                a1 = fmaf(w, p[4096], a1);
                a2 = fmaf(w, p[8192], a2);
                wzs += w;
            }
        }
        float inv = 1.f / wzs;
        a0 *= inv; a1 *= inv; a2 *= inv;
        float sq = a0 * a0 + a1 * a1 + a2 * a2;
        if (side) pt1[b * N1 + n] = make_float4(-2.f * a0, -2.f * a1, -2.f * a2, sq);
        else      ps1[b * N1 + n] = make_float4(a0, a1, a2, sq);
    }
}

// cosine of two point-major 32-float descriptors (coalesced float4 reads)
__device__ __forceinline__ float cos_pm(const float* __restrict__ sT,
                                        const float* __restrict__ tT,
                                        size_t si, size_t ti) {
    const float4* s = (const float4*)(sT + si * CDESC);
    const float4* t = (const float4*)(tT + ti * CDESC);
    float num = 0.f, s2 = 0.f, t2 = 0.f;
#pragma unroll
    for (int c = 0; c < 8; ++c) {
        float4 a = s[c], g = t[c];
        num = fmaf(a.x, g.x, fmaf(a.y, g.y, fmaf(a.z, g.z, fmaf(a.w, g.w, num))));
        s2  = fmaf(a.x, a.x, fmaf(a.y, a.y, fmaf(a.z, a.z, fmaf(a.w, a.w, s2))));
        t2  = fmaf(g.x, g.x, fmaf(g.y, g.y, fmaf(g.z, g.z, fmaf(g.w, g.w, t2))));
    }
    return num / (fmaxf(sqrtf(s2), 1e-8f) * fmaxf(sqrtf(t2), 1e-8f));
}

// d2 (minus the constant |s|^2 term) from a point P and a pre-transformed candidate Q
__device__ __forceinline__ float dist_pm(float4 P, float4 Q) {
    return fmaf(P.x, Q.x, fmaf(P.y, Q.y, fmaf(P.z, Q.z, Q.w)));
}

// ======================= K3: argmin + cosine (R1 measured-best body) =======================
// LDS-staged candidates (pure float4 copy; pre-transformed in pass2z), batch-16
// min-tree (chain-free) + strict-< batch compare + descending first-match re-scan
// == jnp.argmin first-min, bit-exact. 4 waves x 1024-candidate windows; combine
// via packed (mono(d)<<32|m) u64 keys in reused LDS. 264-ticket finalizer.
__global__ __launch_bounds__(256) void nn_cos_all(
        const float4* __restrict__ ps0, const float4* __restrict__ pt0,
        const float* __restrict__ sd0T, const float* __restrict__ td0T,
        const float4* __restrict__ ps1, const float4* __restrict__ pt1,
        const float* __restrict__ sd1T, const float* __restrict__ td1T,
        float* acc, float* __restrict__ out) {
    extern __shared__ __align__(16) char smraw[];  // 64 KB dynamic
    float4* sm = (float4*)smraw;
    const int tid = threadIdx.x;
    const int bx  = blockIdx.x;

    if (bx < 256) {
        int b = bx >> 6, ptile = bx & 63;
        const float4* tp = pt0 + b * N0;
        for (int i = tid; i < N0; i += 256)        // stage all 4096 targets (64 KB)
            sm[i] = tp[i];                         // pre-transformed in pass2z
        __syncthreads();
        int w = tid >> 6, lane = tid & 63;
        int n = ptile * 64 + lane;
        float4 P = ps0[b * N0 + n];
        const int m0 = w * 1024;                   // this wave's m-window
        float best = FLT_MAX; int bbase = 0;
        for (int k0 = 0; k0 < 1024; k0 += 16) {
            float d[16];
#pragma unroll
            for (int u = 0; u < 16; ++u)
                d[u] = dist_pm(P, sm[m0 + k0 + u]);  // broadcast, conflict-free
            float e0 = fminf(d[0],  d[1]),  e1 = fminf(d[2],  d[3]);
            float e2 = fminf(d[4],  d[5]),  e3 = fminf(d[6],  d[7]);
            float e4 = fminf(d[8],  d[9]),  e5 = fminf(d[10], d[11]);
            float e6 = fminf(d[12], d[13]), e7 = fminf(d[14], d[15]);
            float f0 = fminf(e0, e1), f1 = fminf(e2, e3);
            float f2 = fminf(e4, e5), f3 = fminf(e6, e7);
            float bm = fminf(fminf(f0, f1), fminf(f2, f3));
            if (bm < best) { best = bm; bbase = k0; }  // strict <: keeps first batch
        }
        int bi = 0;
#pragma unroll
        for (int u = 15; u >= 0; --u) {            // descending: ends at FIRST match
            float dv = dist_pm(P, sm[m0 + bbase + u]);
            if (dv == best) bi = u;
        }
        u64 key = ((u64)fbits_mono(best) << 32) | (unsigned)(m0 + bbase + bi);
        __syncthreads();                           // everyone done reading sm
        u64* keys = (u64*)smraw;                   // reuse LDS for combine
        keys[w * 64 + lane] = key;
        __syncthreads();
        if (tid < 64) {
            u64 k0 = keys[tid],       k1 = keys[tid + 64];
            u64 k2 = keys[tid + 128], k3 = keys[tid + 192];
            u64 ka = k0 < k1 ? k0 : k1;
            u64 kb = k2 < k3 ? k2 : k3;
            u64 kk = ka < kb ? ka : kb;            // windows ascending + u64 min
            int nearest = (int)(unsigned)(kk & 0xFFFFFFFFull);
            int n2 = ptile * 64 + tid;
            float cosv = cos_pm(sd0T, td0T, (size_t)b * N0 + n2,
                                (size_t)b * N0 + nearest);
            wave_reduce_atomic(cosv, acc + 0);
        }
    } else {
        int bb = bx - 256;
        int b = bb >> 1;
        const float4* tp = pt1 + b * N1;
        for (int i = tid; i < N1; i += 256)
            sm[i] = tp[i];                         // pre-transformed in pass2z
        __syncthreads();
        int n = (bb & 1) * 256 + tid;
        float4 P = ps1[b * N1 + n];
        float best = FLT_MAX; int bbase = 0;
        for (int k0 = 0; k0 < N1; k0 += 16) {
            float d[16];
#pragma unroll
            for (int u = 0; u < 16; ++u)
                d[u] = dist_pm(P, sm[k0 + u]);
            float e0 = fminf(d[0],  d[1]),  e1 = fminf(d[2],  d[3]);
            float e2 = fminf(d[4],  d[5]),  e3 = fminf(d[6],  d[7]);
            float e4 = fminf(d[8],  d[9]),  e5 = fminf(d[10], d[11]);
            float e6 = fminf(d[12], d[13]), e7 = fminf(d[14], d[15]);
            float f0 = fminf(e0, e1), f1 = fminf(e2, e3);
            float f2 = fminf(e4, e5), f3 = fminf(e6, e7);
            float bm = fminf(fminf(f0, f1), fminf(f2, f3));
            if (bm < best) { best = bm; bbase = k0; }
        }
        int bi = 0;
#pragma unroll
        for (int u = 15; u >= 0; --u) {
            float dv = dist_pm(P, sm[bbase + u]);
            if (dv == best) bi = u;
        }
        float cosv = cos_pm(sd1T, td1T, (size_t)b * N1 + n,
                            (size_t)b * N1 + bbase + bi);
        wave_reduce_atomic(cosv, acc + 1);
    }

    __syncthreads();                               // block's atomics all issued
    if (tid == 0) {
        __threadfence();
        unsigned old = atomicAdd((unsigned*)(acc + 2), 1u);
        if (old == 263u) {                         // last of 264 blocks
            float a0 = atomicAdd(acc + 0, 0.f);
            float a1 = atomicAdd(acc + 1, 0.f);
            out[0] = 1.f - 0.5f * (a0 * (1.f / 16384.f) + a1 * (1.f / 2048.f));
        }
    }
}

extern "C" void kernel_launch(void* const* d_in, const int* in_sizes, int n_in,
                              void* d_out, int out_size, void* d_ws, size_t ws_size,
                              hipStream_t stream) {
    const float* c_src = (const float*)d_in[0];   // [4,3,64,64,64]
    const float* c_tgt = (const float*)d_in[1];
    const float* sd0   = (const float*)d_in[2];   // [4,32,16,16,16]
    const float* td0   = (const float*)d_in[3];
    const float* sd1   = (const float*)d_in[4];   // [4,32,8,8,8]
    const float* td1   = (const float*)d_in[5];
    float* out = (float*)d_out;

    char* ws = (char*)d_ws;
    float* acc  = (float*)ws;                      // [0]=sum0 [1]=sum1 [2]=ticket
    float* x16a = (float*)(ws + 256);              // 196608 floats each [bc][z][16][16]
    float* x16b = x16a + 196608;
    float* x8a  = x16b + 196608;                   // 49152 floats each [bc][z][8][8]
    float* x8b  = x8a + 49152;
    float4* ps0 = (float4*)(x8b + 49152);          // 16384 float4
    float4* pt0 = ps0 + 16384;
    float4* ps1 = pt0 + 16384;                     // 2048 float4
    float4* pt1 = ps1 + 2048;
    float* sd0T = (float*)(pt1 + 2048);            // 524288 floats each
    float* td0T = sd0T + 524288;
    float* sd1T = td0T + 524288;                   // 65536 floats each
    float* td1T = sd1T + 65536;

    pass1_fused<<<dim3(1056, 2), 256, 0, stream>>>(c_src, c_tgt, sd0, td0, sd1, td1,
                                                   x16a, x16b, x8a, x8b,
                                                   sd0T, td0T, sd1T, td1T, acc);
    pass2z<<<144, 256, 0, stream>>>(x16a, x16b, x8a, x8b, ps0, pt0, ps1, pt1);
    nn_cos_all<<<264, 256, 65536, stream>>>(ps0, pt0, sd0T, td0T, ps1, pt1,
                                            sd1T, td1T, acc, out);
}